// Round 1
// baseline (3145.563 us; speedup 1.0000x reference)
//
#include <hip/hip_runtime.h>
#include <hip/hip_bf16.h>
#include <math.h>

#define V_NODES 50000
#define E_EDGES 25000
#define NNZ     600000
#define S_SUB   8
#define K_SUB   16
#define DD      128      // S*K
#define NUM_STEP 4
#define EPSF    1e-10f

// stats layout per side (side = 2*step + {0:Y,1:X}), stride 2177 floats:
// [0] entropy sum; [1..128] colsum; [129..2176] gram (s*256 + i*16 + j)
#define STATS_STRIDE 2177

// ---------------- softmax over groups of 16 (gumbel-softmax X0) -------------
__global__ void softmax16_kernel(const float* __restrict__ emb,
                                 const float* __restrict__ gum,
                                 float* __restrict__ X) {
    int i = blockIdx.x * blockDim.x + threadIdx.x;
    if (i >= V_NODES * DD) return;
    float x = emb[i] + gum[i];          // TAU = 1.0
    float m = x;
    #pragma unroll
    for (int off = 1; off < 16; off <<= 1) m = fmaxf(m, __shfl_xor(m, off, 16));
    float e = expf(x - m);
    float s = e;
    #pragma unroll
    for (int off = 1; off < 16; off <<= 1) s += __shfl_xor(s, off, 16);
    X[i] = e / s;
}

// ---------------- histogram of segment counts (loop-invariant) --------------
__global__ void hist_kernel(const int* __restrict__ Vi, const int* __restrict__ Ei,
                            float* __restrict__ cntV, float* __restrict__ cntE) {
    int n = blockIdx.x * blockDim.x + threadIdx.x;
    if (n >= NNZ) return;
    atomicAdd(&cntV[Vi[n]], 1.0f);
    atomicAdd(&cntE[Ei[n]], 1.0f);
}

// ---------------- gather rows at sidx, atomic-add into rows at didx ---------
__global__ void scatter_add_kernel(const float* __restrict__ src,
                                   float* __restrict__ dst,
                                   const int* __restrict__ sidx,
                                   const int* __restrict__ didx) {
    int i = blockIdx.x * blockDim.x + threadIdx.x;
    if (i >= NNZ * DD) return;
    int n = i >> 7;
    int d = i & 127;
    atomicAdd(&dst[didx[n] * DD + d], src[sidx[n] * DD + d]);
}

// ------- divide sums by counts in place; accumulate entropy/colsum/gram -----
__global__ void finalize_kernel(float* __restrict__ M, const float* __restrict__ cnt,
                                int N, float* __restrict__ stats) {
    int t = threadIdx.x;
    int r = t >> 7;          // row-in-pair (0/1)
    int d = t & 127;         // column
    int s = d >> 4;          // subspace
    int i = d & 15;          // index within subspace

    float ent = 0.f, col = 0.f;
    float gram[16];
    #pragma unroll
    for (int j = 0; j < 16; ++j) gram[j] = 0.f;

    for (int row = blockIdx.x * 2 + r; row < N; row += gridDim.x * 2) {
        float c = cnt[row];
        float y = M[row * DD + d] / fmaxf(c, 1.0f);
        M[row * DD + d] = y;
        ent -= y * logf(y + EPSF);
        col += y;
        #pragma unroll
        for (int j = 0; j < 16; ++j) {
            float yj = __shfl(y, j, 16);   // broadcast within 16-lane subspace group
            gram[j] += y * yj;
        }
    }

    __shared__ float red[256];
    // entropy: full block reduce -> 1 atomic
    red[t] = ent; __syncthreads();
    for (int st = 128; st > 0; st >>= 1) {
        if (t < st) red[t] += red[t + st];
        __syncthreads();
    }
    if (t == 0) atomicAdd(&stats[0], red[0]);
    __syncthreads();
    // colsum: pair reduce (t, t+128 share d) -> 128 atomics per block
    red[t] = col; __syncthreads();
    if (t < 128) atomicAdd(&stats[1 + d], red[t] + red[t + 128]);
    __syncthreads();
    // gram: pair reduce then atomics (16 per thread-half)
    for (int j = 0; j < 16; ++j) {
        red[t] = gram[j]; __syncthreads();
        if (t < 128) atomicAdd(&stats[129 + s * 256 + i * 16 + j], red[t] + red[t + 128]);
        __syncthreads();
    }
}

// ---------------- final loss from the 8 stats blocks ------------------------
__global__ void loss_kernel(const float* __restrict__ stats, float* __restrict__ out) {
    int t = threadIdx.x;
    float acc_l = 0.f, acc_g = 0.f;

    // loss_local: entropy sums / (N*S)
    if (t < 8) {
        float N = (t & 1) ? (float)V_NODES : (float)E_EDGES;
        acc_l = stats[t * STATS_STRIDE] / (N * (float)S_SUB);
    }

    // p-terms: += mean_s(sum_k p*log(p+eps)) = (1/S) * sum over 128 cols
    for (int u = t; u < 8 * 128; u += blockDim.x) {
        int side = u >> 7, d = u & 127;
        float N = (side & 1) ? (float)V_NODES : (float)E_EDGES;
        float p = stats[side * STATS_STRIDE + 1 + d] / N;
        acc_g += p * logf(p + EPSF) / (float)S_SUB;
    }

    // discrimination: mean over (s,i) of (logsumexp_j C[i,:] - C[i,i])
    for (int u = t; u < 8 * 8 * 16; u += blockDim.x) {
        int side = u >> 7;
        int s = (u >> 4) & 7;
        int i = u & 15;
        const float* G = stats + side * STATS_STRIDE + 129 + s * 256;
        float nii = sqrtf(G[i * 16 + i]);
        float C[16];
        float m = -INFINITY;
        #pragma unroll
        for (int j = 0; j < 16; ++j) {
            float njj = sqrtf(G[j * 16 + j]);
            float c = G[i * 16 + j] / fmaxf(nii * njj, EPSF);
            C[j] = c;
            m = fmaxf(m, c);
        }
        float sum = 0.f;
        #pragma unroll
        for (int j = 0; j < 16; ++j) sum += expf(C[j] - m);
        float lse = logf(sum) + m;
        acc_g += (lse - C[i]) / (float)(S_SUB * K_SUB);
    }

    __shared__ float redl[256], redg[256];
    redl[t] = acc_l; redg[t] = acc_g; __syncthreads();
    for (int st = 128; st > 0; st >>= 1) {
        if (t < st) { redl[t] += redl[t + st]; redg[t] += redg[t + st]; }
        __syncthreads();
    }
    if (t == 0) { out[0] = redl[0]; out[1] = redg[0]; }
}

extern "C" void kernel_launch(void* const* d_in, const int* in_sizes, int n_in,
                              void* d_out, int out_size, void* d_ws, size_t ws_size,
                              hipStream_t stream) {
    const float* emb = (const float*)d_in[0];
    const float* gum = (const float*)d_in[1];
    const int*   Vi  = (const int*)d_in[2];
    const int*   Ei  = (const int*)d_in[3];
    float* out = (float*)d_out;

    char* ws = (char*)d_ws;
    size_t off = 0;
    float* X = (float*)(ws + off);    off += (size_t)V_NODES * DD * 4;   // 25.6 MB
    float* Y = (float*)(ws + off);    off += (size_t)E_EDGES * DD * 4;   // 12.8 MB
    float* cntV = (float*)(ws + off); off += (size_t)V_NODES * 4;
    float* cntE = (float*)(ws + off); off += (size_t)E_EDGES * 4;
    float* stats = (float*)(ws + off); off += (size_t)8 * STATS_STRIDE * 4;

    // zero the accumulators (counts, stats) every launch
    hipMemsetAsync(cntV, 0, ((size_t)V_NODES + E_EDGES) * 4, stream);
    hipMemsetAsync(stats, 0, (size_t)8 * STATS_STRIDE * 4, stream);

    softmax16_kernel<<<(V_NODES * DD + 255) / 256, 256, 0, stream>>>(emb, gum, X);
    hist_kernel<<<(NNZ + 255) / 256, 256, 0, stream>>>(Vi, Ei, cntV, cntE);

    const int scatter_blocks = (NNZ * DD + 255) / 256;
    for (int step = 0; step < NUM_STEP; ++step) {
        // Y = scatter_mean(X[Vi], Ei)
        hipMemsetAsync(Y, 0, (size_t)E_EDGES * DD * 4, stream);
        scatter_add_kernel<<<scatter_blocks, 256, 0, stream>>>(X, Y, Vi, Ei);
        finalize_kernel<<<128, 256, 0, stream>>>(Y, cntE, E_EDGES,
                                                 stats + (2 * step) * STATS_STRIDE);
        // X = scatter_mean(Y[Ei], Vi)
        hipMemsetAsync(X, 0, (size_t)V_NODES * DD * 4, stream);
        scatter_add_kernel<<<scatter_blocks, 256, 0, stream>>>(Y, X, Ei, Vi);
        finalize_kernel<<<128, 256, 0, stream>>>(X, cntV, V_NODES,
                                                 stats + (2 * step + 1) * STATS_STRIDE);
    }

    loss_kernel<<<1, 256, 0, stream>>>(stats, out);
}